// Round 1
// baseline (154.932 us; speedup 1.0000x reference)
//
#include <hip/hip_runtime.h>
#include <hip/hip_bf16.h>
#include <math.h>

#define B_N 4096
#define D_N 768
#define C_N 10

typedef short bf16x8 __attribute__((ext_vector_type(8)));
typedef float f32x4 __attribute__((ext_vector_type(4)));

// ws layout (floats):
//   [0] ce_sum   [1] taml_sum   [2] tals   [3] nvalid
//   [8..18)   counts[10]
//   [32..32+7680)  class sums [10][768]
// byte offset 65536: enorm bf16 [4096*768]  (6291456 bytes)

// ---------------- CE + label histogram ----------------
__global__ void k_ce(const float* __restrict__ logits,
                     const int* __restrict__ labels,
                     float* __restrict__ ws) {
    __shared__ float red[256];
    __shared__ float cnt[C_N];
    int t = threadIdx.x;
    if (t < C_N) cnt[t] = 0.f;
    __syncthreads();

    int row = blockIdx.x * 256 + t;
    int lab = labels[row];
    const float* lp = logits + (size_t)row * C_N;
    float m = lp[0];
#pragma unroll
    for (int c = 1; c < C_N; ++c) m = fmaxf(m, lp[c]);
    float s = 0.f;
#pragma unroll
    for (int c = 0; c < C_N; ++c) s += __expf(lp[c] - m);
    float val = (m + __logf(s)) - lp[lab];   // -log p[label]

    atomicAdd(&cnt[lab], 1.0f);
    red[t] = val;
    __syncthreads();
    for (int off = 128; off; off >>= 1) {
        if (t < off) red[t] += red[t + off];
        __syncthreads();
    }
    if (t == 0) atomicAdd(&ws[0], red[0]);
    if (t < C_N) atomicAdd(&ws[8 + t], cnt[t]);
}

// ---------------- per-class segment sums ----------------
// grid (3, 32): blockIdx.x = 256-col chunk, blockIdx.y = 128-row chunk
__global__ void k_cent(const float* __restrict__ emb,
                       const int* __restrict__ labels,
                       float* __restrict__ ws) {
    __shared__ float lacc[C_N * 256];
    int t = threadIdx.x;
    int col = blockIdx.x * 256 + t;
#pragma unroll
    for (int c = 0; c < C_N; ++c) lacc[c * 256 + t] = 0.f;

    int rbase = blockIdx.y * 128;
    for (int r = 0; r < 128; ++r) {
        int b = rbase + r;
        int lab = labels[b];
        float v = emb[(size_t)b * D_N + col];
        lacc[lab * 256 + t] += v;
    }
    float* sums = ws + 32;
#pragma unroll
    for (int c = 0; c < C_N; ++c)
        atomicAdd(&sums[c * D_N + col], lacc[c * 256 + t]);
}

// ---------------- row-normalize -> bf16 ----------------
// one block per row, 256 threads, 3 elems/thread
__global__ void k_enorm(const float* __restrict__ emb,
                        __hip_bfloat16* __restrict__ enorm) {
    __shared__ float red[256];
    int t = threadIdx.x;
    size_t base = (size_t)blockIdx.x * D_N;
    float v0 = emb[base + t];
    float v1 = emb[base + t + 256];
    float v2 = emb[base + t + 512];
    red[t] = v0 * v0 + v1 * v1 + v2 * v2;
    __syncthreads();
    for (int off = 128; off; off >>= 1) {
        if (t < off) red[t] += red[t + off];
        __syncthreads();
    }
    float inv = 1.0f / fmaxf(sqrtf(red[0]), 1e-12f);
    enorm[base + t]       = __float2bfloat16(v0 * inv);
    enorm[base + t + 256] = __float2bfloat16(v1 * inv);
    enorm[base + t + 512] = __float2bfloat16(v2 * inv);
}

// ---------------- fused TAML GEMM ----------------
// 128x128 tile per block, 4 waves (2x2), each wave 4x4 grid of 16x16x32 MFMA.
// Upper-triangular block grid; per-element weight 2*(i<j).
__global__ __launch_bounds__(256) void k_taml(const __hip_bfloat16* __restrict__ E,
                                              const int* __restrict__ labels,
                                              const float* __restrict__ topo,
                                              float* __restrict__ ws) {
    int bi = blockIdx.y, bj = blockIdx.x;
    if (bj < bi) return;   // uniform exit, before any barrier

    __shared__ __hip_bfloat16 As[128][32];
    __shared__ __hip_bfloat16 Bs[128][32];
    __shared__ int lA[128], lB[128];
    __shared__ float topo_s[C_N * C_N];
    __shared__ float wsum[4];

    int t = threadIdx.x;
    int ib0 = bi * 128, jb0 = bj * 128;
    if (t < 128) lA[t] = labels[ib0 + t];
    else         lB[t - 128] = labels[jb0 + t - 128];
    if (t < C_N * C_N) topo_s[t] = topo[t];

    int w = t >> 6, lane = t & 63;
    int quad = lane >> 4, m16 = lane & 15;
    int wrow = (w >> 1) * 64, wcol = (w & 1) * 64;

    f32x4 acc[4][4];
    f32x4 z = {0.f, 0.f, 0.f, 0.f};
#pragma unroll
    for (int mt = 0; mt < 4; ++mt)
#pragma unroll
        for (int nt = 0; nt < 4; ++nt) acc[mt][nt] = z;

    int r = t >> 1, h = t & 1;   // staging: 2 threads per row, 16 bf16 each

    for (int k0 = 0; k0 < D_N; k0 += 32) {
        __syncthreads();
        const float4* sa = (const float4*)(E + (size_t)(ib0 + r) * D_N + k0 + h * 16);
        float4* da = (float4*)(&As[r][h * 16]);
        da[0] = sa[0]; da[1] = sa[1];
        const float4* sb = (const float4*)(E + (size_t)(jb0 + r) * D_N + k0 + h * 16);
        float4* db = (float4*)(&Bs[r][h * 16]);
        db[0] = sb[0]; db[1] = sb[1];
        __syncthreads();

        bf16x8 af[4], bfr[4];
#pragma unroll
        for (int x = 0; x < 4; ++x) {
            af[x]  = *(const bf16x8*)(&As[wrow + x * 16 + m16][quad * 8]);
            bfr[x] = *(const bf16x8*)(&Bs[wcol + x * 16 + m16][quad * 8]);
        }
#pragma unroll
        for (int mt = 0; mt < 4; ++mt)
#pragma unroll
            for (int nt = 0; nt < 4; ++nt)
                acc[mt][nt] = __builtin_amdgcn_mfma_f32_16x16x32_bf16(
                    af[mt], bfr[nt], acc[mt][nt], 0, 0, 0);
    }

    // epilogue: relu(sim - 1 + margin) over valid (li!=lj) upper-tri pairs, x2
    float local = 0.f;
#pragma unroll
    for (int mt = 0; mt < 4; ++mt) {
#pragma unroll
        for (int nt = 0; nt < 4; ++nt) {
#pragma unroll
            for (int reg = 0; reg < 4; ++reg) {
                int il = wrow + mt * 16 + quad * 4 + reg;
                int jl = wcol + nt * 16 + m16;
                int gi = ib0 + il, gj = jb0 + jl;
                int li = lA[il], lj = lB[jl];
                float v = acc[mt][nt][reg] - 1.0f + topo_s[li * C_N + lj];
                if (li != lj && gi < gj && v > 0.f) local += v;
            }
        }
    }
    local *= 2.0f;

    for (int off = 32; off; off >>= 1) local += __shfl_down(local, off, 64);
    if (lane == 0) wsum[w] = local;
    __syncthreads();
    if (t == 0) atomicAdd(&ws[1], wsum[0] + wsum[1] + wsum[2] + wsum[3]);
}

// ---------------- TALS + nvalid ----------------
__global__ void k_tals(const float* __restrict__ topo, float* __restrict__ ws) {
    __shared__ float cents[C_N * 769];   // stride 769 breaks bank aliasing
    __shared__ float edist[C_N * C_N];
    __shared__ float cnt_s[C_N];
    int t = threadIdx.x;   // 128 threads
    const float* counts = ws + 8;
    const float* sums = ws + 32;
    if (t < C_N) cnt_s[t] = counts[t];
    __syncthreads();
    for (int idx = t; idx < C_N * D_N; idx += 128) {
        int c = idx / D_N, d = idx - c * D_N;
        cents[c * 769 + d] = sums[idx] / fmaxf(cnt_s[c], 1.0f);
    }
    __syncthreads();
    if (t < C_N * C_N) {
        int i = t / C_N, j = t - (t / C_N) * C_N;
        float s = 0.f;
        for (int d = 0; d < D_N; ++d) {
            float diff = cents[i * 769 + d] - cents[j * 769 + d];
            s += diff * diff;
        }
        edist[t] = sqrtf(s + 1e-12f);
    }
    __syncthreads();
    if (t == 0) {
        float mx = 0.f;
        for (int p = 0; p < C_N * C_N; ++p) mx = fmaxf(mx, edist[p]);
        float inv = 1.0f / (mx + 1e-8f);
        float accv = 0.f;
        for (int p = 0; p < C_N * C_N; ++p) {
            float d = edist[p] * inv - topo[p];
            accv += d * d;
        }
        ws[2] = accv * (1.0f / (C_N * C_N));
        float s2 = 0.f;
        for (int c = 0; c < C_N; ++c) s2 += cnt_s[c] * cnt_s[c];
        ws[3] = (float)B_N * (float)B_N - s2;
    }
}

// ---------------- combine ----------------
__global__ void k_final(const float* __restrict__ ws, float* __restrict__ out) {
    if (threadIdx.x == 0 && blockIdx.x == 0) {
        float ce   = ws[0] / (float)B_N;
        float tals = ws[2];
        float taml = ws[1] / fmaxf(ws[3], 1.0f);
        out[0] = ce + 0.5f * tals + 0.5f * taml;
        out[1] = ce;
        out[2] = tals;
        out[3] = taml;
    }
}

extern "C" void kernel_launch(void* const* d_in, const int* in_sizes, int n_in,
                              void* d_out, int out_size, void* d_ws, size_t ws_size,
                              hipStream_t stream) {
    const float* logits = (const float*)d_in[0];
    const int*   labels = (const int*)d_in[1];
    const float* emb    = (const float*)d_in[2];
    const float* topo   = (const float*)d_in[3];
    float* ws = (float*)d_ws;
    __hip_bfloat16* enorm = (__hip_bfloat16*)((char*)d_ws + 65536);
    float* out = (float*)d_out;

    hipMemsetAsync(d_ws, 0, 65536, stream);
    k_ce<<<B_N / 256, 256, 0, stream>>>(logits, labels, ws);
    k_cent<<<dim3(3, 32), 256, 0, stream>>>(emb, labels, ws);
    k_enorm<<<B_N, 256, 0, stream>>>(emb, enorm);
    k_taml<<<dim3(32, 32), 256, 0, stream>>>(enorm, labels, topo, ws);
    k_tals<<<1, 128, 0, stream>>>(topo, ws);
    k_final<<<1, 64, 0, stream>>>(ws, out);
}